// Round 11
// baseline (36.448 us; speedup 1.0000x reference)
//
#include <hip/hip_runtime.h>
#include <hip/hip_bf16.h>

#define BATCH 64
#define NADJ  512
#define F     128
#define CROP0 128
#define CROP1 384
#define CN    256
#define BN_EPS 1e-5f

typedef __attribute__((ext_vector_type(8))) short short8;
typedef __attribute__((ext_vector_type(4))) float f32x4;

__device__ __forceinline__ ushort f2bf(float x) {
  __hip_bfloat16 h = __float2bfloat16(x);  // RNE
  return *reinterpret_cast<ushort*>(&h);
}

// XCD-aligned swizzle: all 8 tiles of batch b land on XCD (b&7).
__device__ __forceinline__ void swz(int Wd, int& b, int& sub) {
  const int x = Wd & 7, y = Wd >> 3;
  b   = ((y >> 3) << 3) | x;
  sub = y & 7;
}

// ---------------------------------------------------------------------------
// K1: St[b][f][m] = bf16( (input_crop @ W)^T ), m-tile 32 per block.
// Also beta-fills the non-crop rows of out.
// ---------------------------------------------------------------------------
__global__ __launch_bounds__(256) void support_k(
    const float* __restrict__ input, const float* __restrict__ W,
    ushort* __restrict__ St, float* __restrict__ out,
    const float* __restrict__ beta) {
  int b, sub;
  swz(blockIdx.x, b, sub);
  const int m0 = sub * 32;
  __shared__ ushort wt[128][136];  // W^T [f][i]
  __shared__ ushort ain[32][136];  // input tile [m][i]
  const int tid = threadIdx.x;
  const float* inb = input + ((size_t)b * NADJ + CROP0 + m0) * F;

  {
    const int i0 = tid & 63;
    const int fq = (tid >> 6) * 32;
#pragma unroll
    for (int ih = 0; ih < 2; ++ih) {
      const int i = i0 + ih * 64;
      const float* wr = &W[(size_t)i * F + fq];
      float4 v[8];
#pragma unroll
      for (int q = 0; q < 8; ++q)
        v[q] = reinterpret_cast<const float4*>(wr)[q];
#pragma unroll
      for (int q = 0; q < 8; ++q) {
        wt[fq + q * 4 + 0][i] = f2bf(v[q].x);
        wt[fq + q * 4 + 1][i] = f2bf(v[q].y);
        wt[fq + q * 4 + 2][i] = f2bf(v[q].z);
        wt[fq + q * 4 + 3][i] = f2bf(v[q].w);
      }
    }
  }
  for (int idx = tid; idx < 32 * 32; idx += 256) {
    const int ml = idx >> 5, c4 = (idx & 31) * 4;
    const float4 v =
        *reinterpret_cast<const float4*>(&inb[(size_t)ml * F + c4]);
    *reinterpret_cast<ushort4*>(&ain[ml][c4]) =
        make_ushort4(f2bf(v.x), f2bf(v.y), f2bf(v.z), f2bf(v.w));
  }
  __syncthreads();

  const int l = tid & 63, w = tid >> 6;
  const int lr = l & 15, lg = l >> 4;
  const int msub = (w & 1) * 16;
  const int f0   = (w >> 1) * 64;
  f32x4 acc[4] = {};
#pragma unroll
  for (int ks = 0; ks < 4; ++ks) {
    const int k0 = ks * 32 + lg * 8;
    const short8 av = *reinterpret_cast<const short8*>(&ain[msub + lr][k0]);
#pragma unroll
    for (int fi = 0; fi < 4; ++fi) {
      const short8 bv =
          *reinterpret_cast<const short8*>(&wt[f0 + fi * 16 + lr][k0]);
      acc[fi] =
          __builtin_amdgcn_mfma_f32_16x16x32_bf16(av, bv, acc[fi], 0, 0, 0);
    }
  }
#pragma unroll
  for (int fi = 0; fi < 4; ++fi) {
    const int f = f0 + fi * 16 + lr;
    *reinterpret_cast<ushort4*>(
        &St[((size_t)b * F + f) * CN + m0 + msub + lg * 4]) =
        make_ushort4(f2bf(acc[fi][0]), f2bf(acc[fi][1]), f2bf(acc[fi][2]),
                     f2bf(acc[fi][3]));
  }

  // beta-fill non-crop rows of out
  const int gid = blockIdx.x * 256 + tid;
#pragma unroll
  for (int q = 0; q < 4; ++q) {
    const int g2 = gid + q * 131072;
    const int c4 = (g2 & 31) * 4;
    const int rr = (g2 >> 5) & 255;
    const int bb = g2 >> 13;
    const int n  = rr < 128 ? rr : rr + 256;
    const float4 bv =
        *reinterpret_cast<const float4*>(&beta[(size_t)n * F + c4]);
    *reinterpret_cast<float4*>(&out[((size_t)bb * NADJ + n) * F + c4]) = bv;
  }
}

// ---------------------------------------------------------------------------
// K2: Ocrop[b][n][f] = adj_crop[b][n][:] @ S[b][:][f], n-tile 32 per block.
// ALL global loads pre-issued at entry: adj tile (8 x float4) + entire St[b]
// (16 x uint4 = full 64KB block-wide, chunk-major reg layout). K-loop is
// LDS-only: ds_write chunk from regs -> barrier -> MFMA -> barrier.
// adj read ONCE (no f-split redundancy). 35.3KB LDS, 3 blocks/CU.
// ---------------------------------------------------------------------------
__global__ __launch_bounds__(256, 3) void aggregate_k(
    const float* __restrict__ adj, const ushort* __restrict__ St,
    float* __restrict__ Ocrop) {
  int b, sub;
  swz(blockIdx.x, b, sub);
  const int n0 = sub * 32;
  __shared__ ushort adt[32][264];  // adj tile bf16 [n][k], 528B stride
  __shared__ ushort stl[128][72];  // St chunk [f][kl], 144B stride
  const int tid = threadIdx.x;
  const float*  adjb = adj + ((size_t)b * NADJ + CROP0 + n0) * NADJ + CROP0;
  const ushort* Stb  = St + (size_t)b * F * CN;

  // --- pre-issue ALL global loads (24 x 16B per thread, independent) ---
  const int ar = tid >> 6;        // adj row group 0..3
  const int ac = (tid & 63) * 4;  // adj col
  float4 areg[8];
#pragma unroll
  for (int q = 0; q < 8; ++q)
    areg[q] = *reinterpret_cast<const float4*>(
        &adjb[(size_t)(ar + q * 4) * NADJ + ac]);

  const int srow = tid >> 3;       // f-row offset within 32-group
  const int scol = (tid & 7) * 8;  // m-ushort offset within 64-chunk
  uint4 sreg[16];                  // [c][j]: St[f=j*32+srow][m=c*64+scol..]
#pragma unroll
  for (int c = 0; c < 4; ++c)
#pragma unroll
    for (int j = 0; j < 4; ++j)
      sreg[c * 4 + j] = *reinterpret_cast<const uint4*>(
          &Stb[(size_t)(j * 32 + srow) * CN + c * 64 + scol]);

  // --- adj -> LDS (bf16) ---
#pragma unroll
  for (int q = 0; q < 8; ++q)
    *reinterpret_cast<ushort4*>(&adt[ar + q * 4][ac]) =
        make_ushort4(f2bf(areg[q].x), f2bf(areg[q].y), f2bf(areg[q].z),
                     f2bf(areg[q].w));
  __syncthreads();

  const int l = tid & 63, w = tid >> 6;
  const int lr = l & 15, lg = l >> 4;
  const int nsub = (w & 1) * 16;
  const int f0   = (w >> 1) * 64;
  f32x4 acc[4] = {};

  for (int c = 0; c < 4; ++c) {
    // St chunk c: regs -> LDS (static reg indices; 2-way bank = free)
#pragma unroll
    for (int j = 0; j < 4; ++j)
      *reinterpret_cast<uint4*>(&stl[j * 32 + srow][scol]) = sreg[c * 4 + j];
    __syncthreads();
#pragma unroll
    for (int ks = 0; ks < 2; ++ks) {
      const int kl = ks * 32 + lg * 8;
      const short8 av =
          *reinterpret_cast<const short8*>(&adt[nsub + lr][c * 64 + kl]);
#pragma unroll
      for (int fi = 0; fi < 4; ++fi) {
        const short8 bv =
            *reinterpret_cast<const short8*>(&stl[f0 + fi * 16 + lr][kl]);
        acc[fi] =
            __builtin_amdgcn_mfma_f32_16x16x32_bf16(av, bv, acc[fi], 0, 0, 0);
      }
    }
    __syncthreads();
  }

#pragma unroll
  for (int fi = 0; fi < 4; ++fi) {
    const int f = f0 + fi * 16 + lr;
    const int n = n0 + nsub + lg * 4;
#pragma unroll
    for (int r = 0; r < 4; ++r)
      Ocrop[((size_t)b * CN + n + r) * F + f] = acc[fi][r];
  }
}

// ---------------------------------------------------------------------------
// K3: BN stats + normalize from dense Ocrop -> out crop rows.
// ---------------------------------------------------------------------------
__global__ __launch_bounds__(256) void bn_crop(
    const float* __restrict__ Ocrop, float* __restrict__ out,
    const float* __restrict__ gamma, const float* __restrict__ beta) {
  __shared__ float s_l[256], s2_l[256], m_l[64], r_l[64];
  const int tid = threadIdx.x;
  const int jl = tid & 63, bg = tid >> 6;
  const int j  = blockIdx.x * 64 + jl;  // 0..32767 = nl*128+f
  const int nl = j >> 7, f = j & 127;
  const int nf = (CROP0 + nl) * F + f;
  const float* p = Ocrop + (size_t)j + (size_t)bg * 16 * CN * F;

  float x[16];
  float s = 0.f, s2 = 0.f;
#pragma unroll
  for (int bb = 0; bb < 16; ++bb) {
    x[bb] = p[(size_t)bb * CN * F];
    s += x[bb];
    s2 += x[bb] * x[bb];
  }
  s_l[tid]  = s;
  s2_l[tid] = s2;
  __syncthreads();
  if (tid < 64) {
    s  = s_l[jl] + s_l[64 + jl] + s_l[128 + jl] + s_l[192 + jl];
    s2 = s2_l[jl] + s2_l[64 + jl] + s2_l[128 + jl] + s2_l[192 + jl];
    const float mean = s * (1.f / BATCH);
    const float var  = s2 * (1.f / BATCH) - mean * mean;
    m_l[jl] = mean;
    r_l[jl] = rsqrtf(var + BN_EPS);
  }
  __syncthreads();
  const float mean = m_l[jl];
  const float a    = r_l[jl] * gamma[nf];
  const float c    = beta[nf] - mean * a;
#pragma unroll
  for (int bb = 0; bb < 16; ++bb)
    out[(size_t)nf + (size_t)(bg * 16 + bb) * NADJ * F] = x[bb] * a + c;
}

extern "C" void kernel_launch(void* const* d_in, const int* in_sizes, int n_in,
                              void* d_out, int out_size, void* d_ws,
                              size_t ws_size, hipStream_t stream) {
  const float* input = (const float*)d_in[0];
  const float* adj   = (const float*)d_in[1];
  const float* W     = (const float*)d_in[2];
  const float* gamma = (const float*)d_in[3];
  const float* beta  = (const float*)d_in[4];
  float* out = (float*)d_out;

  ushort* St    = (ushort*)d_ws;                            // 4 MB
  float*  Ocrop = (float*)((char*)d_ws + 4 * 1024 * 1024);  // 8.4 MB

  support_k<<<512, 256, 0, stream>>>(input, W, St, out, beta);
  aggregate_k<<<512, 256, 0, stream>>>(adj, St, Ocrop);
  bn_crop<<<512, 256, 0, stream>>>(Ocrop, out, gamma, beta);
}

// Round 12
// 31.687 us; speedup vs baseline: 1.1503x; 1.1503x over previous
//
#include <hip/hip_runtime.h>
#include <hip/hip_bf16.h>

#define BATCH 64
#define NADJ  512
#define F     128
#define CROP0 128
#define CROP1 384
#define CN    256
#define BN_EPS 1e-5f

typedef __attribute__((ext_vector_type(8))) short short8;
typedef __attribute__((ext_vector_type(4))) float f32x4;

__device__ __forceinline__ ushort f2bf(float x) {
  __hip_bfloat16 h = __float2bfloat16(x);  // RNE
  return *reinterpret_cast<ushort*>(&h);
}

// ---------------------------------------------------------------------------
// K1: St[b][f][m] = bf16( (input_crop @ W)^T ), m-tile 32 per block.
// grid 512: x=blk&7 (XCD), b=(y>>3)*8+x keeps St[b] on XCD b&7.
// Also beta-fills the non-crop rows of out.
// ---------------------------------------------------------------------------
__global__ __launch_bounds__(256) void support_k(
    const float* __restrict__ input, const float* __restrict__ W,
    ushort* __restrict__ St, float* __restrict__ out,
    const float* __restrict__ beta) {
  const int x = blockIdx.x & 7, y = blockIdx.x >> 3;
  const int b  = ((y >> 3) << 3) | x;
  const int m0 = (y & 7) * 32;
  __shared__ ushort wt[128][136];  // W^T [f][i]
  __shared__ ushort ain[32][136];  // input tile [m][i]
  const int tid = threadIdx.x;
  const float* inb = input + ((size_t)b * NADJ + CROP0 + m0) * F;

  {
    const int i0 = tid & 63;
    const int fq = (tid >> 6) * 32;
#pragma unroll
    for (int ih = 0; ih < 2; ++ih) {
      const int i = i0 + ih * 64;
      const float* wr = &W[(size_t)i * F + fq];
      float4 v[8];
#pragma unroll
      for (int q = 0; q < 8; ++q)
        v[q] = reinterpret_cast<const float4*>(wr)[q];
#pragma unroll
      for (int q = 0; q < 8; ++q) {
        wt[fq + q * 4 + 0][i] = f2bf(v[q].x);
        wt[fq + q * 4 + 1][i] = f2bf(v[q].y);
        wt[fq + q * 4 + 2][i] = f2bf(v[q].z);
        wt[fq + q * 4 + 3][i] = f2bf(v[q].w);
      }
    }
  }
  for (int idx = tid; idx < 32 * 32; idx += 256) {
    const int ml = idx >> 5, c4 = (idx & 31) * 4;
    const float4 v =
        *reinterpret_cast<const float4*>(&inb[(size_t)ml * F + c4]);
    *reinterpret_cast<ushort4*>(&ain[ml][c4]) =
        make_ushort4(f2bf(v.x), f2bf(v.y), f2bf(v.z), f2bf(v.w));
  }
  __syncthreads();

  const int l = tid & 63, w = tid >> 6;
  const int lr = l & 15, lg = l >> 4;
  const int msub = (w & 1) * 16;
  const int f0   = (w >> 1) * 64;
  f32x4 acc[4] = {};
#pragma unroll
  for (int ks = 0; ks < 4; ++ks) {
    const int k0 = ks * 32 + lg * 8;
    const short8 av = *reinterpret_cast<const short8*>(&ain[msub + lr][k0]);
#pragma unroll
    for (int fi = 0; fi < 4; ++fi) {
      const short8 bv =
          *reinterpret_cast<const short8*>(&wt[f0 + fi * 16 + lr][k0]);
      acc[fi] =
          __builtin_amdgcn_mfma_f32_16x16x32_bf16(av, bv, acc[fi], 0, 0, 0);
    }
  }
#pragma unroll
  for (int fi = 0; fi < 4; ++fi) {
    const int f = f0 + fi * 16 + lr;
    *reinterpret_cast<ushort4*>(
        &St[((size_t)b * F + f) * CN + m0 + msub + lg * 4]) =
        make_ushort4(f2bf(acc[fi][0]), f2bf(acc[fi][1]), f2bf(acc[fi][2]),
                     f2bf(acc[fi][3]));
  }

  // beta-fill non-crop rows of out
  const int gid = blockIdx.x * 256 + tid;
#pragma unroll
  for (int q = 0; q < 4; ++q) {
    const int g2 = gid + q * 131072;
    const int c4 = (g2 & 31) * 4;
    const int rr = (g2 >> 5) & 255;
    const int bb = g2 >> 13;
    const int n  = rr < 128 ? rr : rr + 256;
    const float4 bv =
        *reinterpret_cast<const float4*>(&beta[(size_t)n * F + c4]);
    *reinterpret_cast<float4*>(&out[((size_t)bb * NADJ + n) * F + c4]) = bv;
  }
}

// ---------------------------------------------------------------------------
// K2: Ocrop[b][n][f] = adj_crop[b][n][:] @ S[b][:][f].
// 16-row n-tiles, grid 1024 (=16 waves/CU): block stages its 16x256 adj tile
// once (8.4KB LDS, single barrier); each wave owns a disjoint 32-f slice,
// B-frags streamed from XCD-local L2 St (already bf16, zero in-loop cvt).
// No mid-loop barriers; 16 indep loads/wave; TLP covers latency.
// ---------------------------------------------------------------------------
__global__ __launch_bounds__(256) void aggregate_k(
    const float* __restrict__ adj, const ushort* __restrict__ St,
    float* __restrict__ Ocrop) {
  const int x = blockIdx.x & 7, y = blockIdx.x >> 3;  // grid 1024
  const int b  = ((y >> 4) << 3) | x;   // batch; 16 tiles of b on XCD x
  const int n0 = (y & 15) * 16;
  __shared__ ushort adt[16][264];       // adj tile bf16, 528B row stride
  const int tid = threadIdx.x;
  const float* adjb = adj + ((size_t)b * NADJ + CROP0 + n0) * NADJ + CROP0;

  // stage adj 16x256 fp32 -> bf16 (coalesced 64B per 16-lane group)
  {
    const int r  = tid >> 4;
    const int c0 = (tid & 15) * 16;
    const float* src = &adjb[(size_t)r * NADJ + c0];
    float4 v[4];
#pragma unroll
    for (int q = 0; q < 4; ++q)
      v[q] = reinterpret_cast<const float4*>(src)[q];
#pragma unroll
    for (int q = 0; q < 4; ++q)
      *reinterpret_cast<ushort4*>(&adt[r][c0 + q * 4]) =
          make_ushort4(f2bf(v[q].x), f2bf(v[q].y), f2bf(v[q].z),
                       f2bf(v[q].w));
  }
  __syncthreads();

  const int l = tid & 63, w = tid >> 6;
  const int lr = l & 15, lg = l >> 4;
  const int f0 = w * 32;  // wave-owned f slice (disjoint across 4 waves)
  const ushort* s0 =
      St + (size_t)b * F * CN + (size_t)(f0 + lr) * CN;
  const ushort* s1 = s0 + (size_t)16 * CN;
  f32x4 acc[2] = {};
#pragma unroll
  for (int ks = 0; ks < 8; ++ks) {
    const int k0 = ks * 32 + lg * 8;
    const short8 av = *reinterpret_cast<const short8*>(&adt[lr][k0]);
    const short8 b0 = *reinterpret_cast<const short8*>(&s0[k0]);
    const short8 b1 = *reinterpret_cast<const short8*>(&s1[k0]);
    acc[0] = __builtin_amdgcn_mfma_f32_16x16x32_bf16(av, b0, acc[0], 0, 0, 0);
    acc[1] = __builtin_amdgcn_mfma_f32_16x16x32_bf16(av, b1, acc[1], 0, 0, 0);
  }
  // D: col(f)=lane&15, row(n)=4*(lane>>4)+reg
#pragma unroll
  for (int fi = 0; fi < 2; ++fi) {
    const int f = f0 + fi * 16 + lr;
    const int n = n0 + lg * 4;
#pragma unroll
    for (int r = 0; r < 4; ++r)
      Ocrop[((size_t)b * CN + n + r) * F + f] = acc[fi][r];
  }
}

// ---------------------------------------------------------------------------
// K3: BN stats + normalize from dense Ocrop -> out crop rows.
// ---------------------------------------------------------------------------
__global__ __launch_bounds__(256) void bn_crop(
    const float* __restrict__ Ocrop, float* __restrict__ out,
    const float* __restrict__ gamma, const float* __restrict__ beta) {
  __shared__ float s_l[256], s2_l[256], m_l[64], r_l[64];
  const int tid = threadIdx.x;
  const int jl = tid & 63, bg = tid >> 6;
  const int j  = blockIdx.x * 64 + jl;  // 0..32767 = nl*128+f
  const int nl = j >> 7, f = j & 127;
  const int nf = (CROP0 + nl) * F + f;
  const float* p = Ocrop + (size_t)j + (size_t)bg * 16 * CN * F;

  float x[16];
  float s = 0.f, s2 = 0.f;
#pragma unroll
  for (int bb = 0; bb < 16; ++bb) {
    x[bb] = p[(size_t)bb * CN * F];
    s += x[bb];
    s2 += x[bb] * x[bb];
  }
  s_l[tid]  = s;
  s2_l[tid] = s2;
  __syncthreads();
  if (tid < 64) {
    s  = s_l[jl] + s_l[64 + jl] + s_l[128 + jl] + s_l[192 + jl];
    s2 = s2_l[jl] + s2_l[64 + jl] + s2_l[128 + jl] + s2_l[192 + jl];
    const float mean = s * (1.f / BATCH);
    const float var  = s2 * (1.f / BATCH) - mean * mean;
    m_l[jl] = mean;
    r_l[jl] = rsqrtf(var + BN_EPS);
  }
  __syncthreads();
  const float mean = m_l[jl];
  const float a    = r_l[jl] * gamma[nf];
  const float c    = beta[nf] - mean * a;
#pragma unroll
  for (int bb = 0; bb < 16; ++bb)
    out[(size_t)nf + (size_t)(bg * 16 + bb) * NADJ * F] = x[bb] * a + c;
}

extern "C" void kernel_launch(void* const* d_in, const int* in_sizes, int n_in,
                              void* d_out, int out_size, void* d_ws,
                              size_t ws_size, hipStream_t stream) {
  const float* input = (const float*)d_in[0];
  const float* adj   = (const float*)d_in[1];
  const float* W     = (const float*)d_in[2];
  const float* gamma = (const float*)d_in[3];
  const float* beta  = (const float*)d_in[4];
  float* out = (float*)d_out;

  ushort* St    = (ushort*)d_ws;                            // 4 MB
  float*  Ocrop = (float*)((char*)d_ws + 4 * 1024 * 1024);  // 8.4 MB

  support_k<<<512, 256, 0, stream>>>(input, W, St, out, beta);
  aggregate_k<<<1024, 256, 0, stream>>>(adj, St, Ocrop);
  bn_crop<<<512, 256, 0, stream>>>(Ocrop, out, gamma, beta);
}

// Round 13
// 28.930 us; speedup vs baseline: 1.2599x; 1.0953x over previous
//
#include <hip/hip_runtime.h>
#include <hip/hip_bf16.h>

#define BATCH 64
#define NADJ  512
#define F     128
#define CROP0 128
#define CROP1 384
#define CN    256
#define BN_EPS 1e-5f

typedef __attribute__((ext_vector_type(8))) short short8;
typedef __attribute__((ext_vector_type(4))) float f32x4;

__device__ __forceinline__ ushort f2bf(float x) {
  __hip_bfloat16 h = __float2bfloat16(x);  // RNE
  return *reinterpret_cast<ushort*>(&h);
}

__device__ __forceinline__ short8 cvt8(const float4 a, const float4 b) {
  short8 r;
  r[0] = (short)f2bf(a.x); r[1] = (short)f2bf(a.y);
  r[2] = (short)f2bf(a.z); r[3] = (short)f2bf(a.w);
  r[4] = (short)f2bf(b.x); r[5] = (short)f2bf(b.y);
  r[6] = (short)f2bf(b.z); r[7] = (short)f2bf(b.w);
  return r;
}

// ---------------------------------------------------------------------------
// KA: fused support+aggregate, 2 blocks per batch (half = 128 n-rows each).
// Per block: W^T -> LDS once; S[b] = input_crop[b] @ W computed chunk-wise
// into LDS stl[f][m] (full 128x256, 67.6KB); then BARRIER-FREE aggregation:
// each of 8 waves owns 16 n-rows, A-frags streamed from global adj (fp32,
// cvt in reg, every byte used once), B-frags = ds_read_b128 from stl
// (528B row stride -> 2-way bank alias = free). No St global round-trip.
// LDS total 119.8KB (1 block/CU). 2x redundant S-compute is ~0.5 GFLOP.
// ---------------------------------------------------------------------------
__global__ __launch_bounds__(512, 1) void gcn_ka(
    const float* __restrict__ input, const float* __restrict__ adj,
    const float* __restrict__ W, float* __restrict__ Ocrop) {
  const int b    = blockIdx.x >> 1;
  const int half = blockIdx.x & 1;
  __shared__ ushort wt[128][136];   // W^T [f][i]        34816 B
  __shared__ ushort ain[64][136];   // input chunk [m][i] 17408 B
  __shared__ ushort stl[128][264];  // S^T full [f][m]    67584 B
  const int tid = threadIdx.x;
  const int l = tid & 63, w = tid >> 6;
  const int lr = l & 15, lg = l >> 4;

  // ---- stage W^T (once): i=(tid&63)+{0,64}, f-group=(tid>>6)*16 ----
  {
    const int i0 = tid & 63;
    const int fq = (tid >> 6) * 16;
#pragma unroll
    for (int ih = 0; ih < 2; ++ih) {
      const int i = i0 + ih * 64;
      const float* wr = &W[(size_t)i * F + fq];
      float4 v[4];
#pragma unroll
      for (int q = 0; q < 4; ++q)
        v[q] = reinterpret_cast<const float4*>(wr)[q];
#pragma unroll
      for (int q = 0; q < 4; ++q) {
        wt[fq + q * 4 + 0][i] = f2bf(v[q].x);
        wt[fq + q * 4 + 1][i] = f2bf(v[q].y);
        wt[fq + q * 4 + 2][i] = f2bf(v[q].z);
        wt[fq + q * 4 + 3][i] = f2bf(v[q].w);
      }
    }
  }

  // ---- S[b] in 4 m-chunks of 64 ----
  const float* inb = input + ((size_t)b * NADJ + CROP0) * F;
  const int msub = (w & 3) * 16;   // wave m-subtile within chunk
  const int sf0  = (w >> 2) * 64;  // wave f-half
  for (int mc = 0; mc < CN; mc += 64) {
    if (mc > 0) __syncthreads();  // prior chunk's ain reads done
    // stage input chunk 64x128 fp32 -> bf16 (coalesced)
    for (int idx = tid; idx < 64 * 32; idx += 512) {
      const int ml = idx >> 5, c4 = (idx & 31) * 4;
      const float4 v = *reinterpret_cast<const float4*>(
          &inb[(size_t)(mc + ml) * F + c4]);
      *reinterpret_cast<ushort4*>(&ain[ml][c4]) =
          make_ushort4(f2bf(v.x), f2bf(v.y), f2bf(v.z), f2bf(v.w));
    }
    __syncthreads();
    f32x4 sacc[4] = {};
#pragma unroll
    for (int ks = 0; ks < 4; ++ks) {
      const int k0 = ks * 32 + lg * 8;
      const short8 av = *reinterpret_cast<const short8*>(&ain[msub + lr][k0]);
#pragma unroll
      for (int fi = 0; fi < 4; ++fi) {
        const short8 bv =
            *reinterpret_cast<const short8*>(&wt[sf0 + fi * 16 + lr][k0]);
        sacc[fi] =
            __builtin_amdgcn_mfma_f32_16x16x32_bf16(av, bv, sacc[fi], 0, 0, 0);
      }
    }
    // D: col(f)=lane&15, row(m)=4*(lane>>4)+reg -> stl[f][m] ushort4
#pragma unroll
    for (int fi = 0; fi < 4; ++fi)
      *reinterpret_cast<ushort4*>(
          &stl[sf0 + fi * 16 + lr][mc + msub + lg * 4]) =
          make_ushort4(f2bf(sacc[fi][0]), f2bf(sacc[fi][1]),
                       f2bf(sacc[fi][2]), f2bf(sacc[fi][3]));
  }
  __syncthreads();  // stl complete

  // ---- barrier-free aggregation: wave w owns rows n0..n0+15 ----
  const int n0 = half * 128 + w * 16;
  const float* a0 =
      adj + ((size_t)b * NADJ + CROP0 + n0 + lr) * NADJ + CROP0;
  f32x4 acc[8] = {};
#pragma unroll
  for (int ks = 0; ks < 8; ++ks) {
    const int k0 = ks * 32 + lg * 8;
    const float4 x0 = *reinterpret_cast<const float4*>(&a0[k0]);
    const float4 x1 = *reinterpret_cast<const float4*>(&a0[k0 + 4]);
    const short8 av = cvt8(x0, x1);
#pragma unroll
    for (int fi = 0; fi < 8; ++fi) {
      const short8 bv =
          *reinterpret_cast<const short8*>(&stl[fi * 16 + lr][k0]);
      acc[fi] =
          __builtin_amdgcn_mfma_f32_16x16x32_bf16(av, bv, acc[fi], 0, 0, 0);
    }
  }
  // D: col(f)=lane&15, row(n)=4*(lane>>4)+reg
#pragma unroll
  for (int fi = 0; fi < 8; ++fi) {
    const int f = fi * 16 + lr;
    const int n = n0 + lg * 4;
#pragma unroll
    for (int r = 0; r < 4; ++r)
      Ocrop[((size_t)b * CN + n + r) * F + f] = acc[fi][r];
  }
}

// ---------------------------------------------------------------------------
// KB: BN stats + normalize crop rows -> out, plus beta-fill non-crop rows.
// ---------------------------------------------------------------------------
__global__ __launch_bounds__(256) void gcn_kb(
    const float* __restrict__ Ocrop, float* __restrict__ out,
    const float* __restrict__ gamma, const float* __restrict__ beta) {
  __shared__ float s_l[256], s2_l[256], m_l[64], r_l[64];
  const int tid = threadIdx.x;
  const int jl = tid & 63, bg = tid >> 6;
  const int j  = blockIdx.x * 64 + jl;  // 0..32767 = nl*128+f
  const int nl = j >> 7, f = j & 127;
  const int nf = (CROP0 + nl) * F + f;
  const float* p = Ocrop + (size_t)j + (size_t)bg * 16 * CN * F;

  float x[16];
  float s = 0.f, s2 = 0.f;
#pragma unroll
  for (int bb = 0; bb < 16; ++bb) {
    x[bb] = p[(size_t)bb * CN * F];
    s += x[bb];
    s2 += x[bb] * x[bb];
  }
  s_l[tid]  = s;
  s2_l[tid] = s2;
  __syncthreads();
  if (tid < 64) {
    s  = s_l[jl] + s_l[64 + jl] + s_l[128 + jl] + s_l[192 + jl];
    s2 = s2_l[jl] + s2_l[64 + jl] + s2_l[128 + jl] + s2_l[192 + jl];
    const float mean = s * (1.f / BATCH);
    const float var  = s2 * (1.f / BATCH) - mean * mean;
    m_l[jl] = mean;
    r_l[jl] = rsqrtf(var + BN_EPS);
  }
  __syncthreads();
  const float mean = m_l[jl];
  const float a    = r_l[jl] * gamma[nf];
  const float c    = beta[nf] - mean * a;
#pragma unroll
  for (int bb = 0; bb < 16; ++bb)
    out[(size_t)nf + (size_t)(bg * 16 + bb) * NADJ * F] = x[bb] * a + c;

  // beta-fill the non-crop rows: 64b x 256 rows x 128f
  const int gid0 = blockIdx.x * 256 + tid;
#pragma unroll
  for (int q = 0; q < 4; ++q) {
    const int gid = gid0 + q * 131072;
    const int c4  = (gid & 31) * 4;
    const int rr  = (gid >> 5) & 255;
    const int bb  = gid >> 13;
    const int n   = rr < 128 ? rr : rr + 256;
    const float4 bv =
        *reinterpret_cast<const float4*>(&beta[(size_t)n * F + c4]);
    *reinterpret_cast<float4*>(&out[((size_t)bb * NADJ + n) * F + c4]) = bv;
  }
}

extern "C" void kernel_launch(void* const* d_in, const int* in_sizes, int n_in,
                              void* d_out, int out_size, void* d_ws,
                              size_t ws_size, hipStream_t stream) {
  const float* input = (const float*)d_in[0];
  const float* adj   = (const float*)d_in[1];
  const float* W     = (const float*)d_in[2];
  const float* gamma = (const float*)d_in[3];
  const float* beta  = (const float*)d_in[4];
  float* out = (float*)d_out;

  float* Ocrop = (float*)d_ws;  // 64*256*128 fp32 = 8.4 MB

  gcn_ka<<<128, 512, 0, stream>>>(input, adj, W, Ocrop);
  gcn_kb<<<512, 256, 0, stream>>>(Ocrop, out, gamma, beta);
}

// Round 14
// 27.064 us; speedup vs baseline: 1.3467x; 1.0689x over previous
//
#include <hip/hip_runtime.h>
#include <hip/hip_bf16.h>

#define BATCH 64
#define NADJ  512
#define F     128
#define CROP0 128
#define CROP1 384
#define CN    256
#define BN_EPS 1e-5f

typedef __attribute__((ext_vector_type(8))) short short8;
typedef __attribute__((ext_vector_type(4))) float f32x4;

__device__ __forceinline__ ushort f2bf(float x) {
  __hip_bfloat16 h = __float2bfloat16(x);  // RNE
  return *reinterpret_cast<ushort*>(&h);
}

__device__ __forceinline__ short8 cvt8(const float4 a, const float4 b) {
  short8 r;
  r[0] = (short)f2bf(a.x); r[1] = (short)f2bf(a.y);
  r[2] = (short)f2bf(a.z); r[3] = (short)f2bf(a.w);
  r[4] = (short)f2bf(b.x); r[5] = (short)f2bf(b.y);
  r[6] = (short)f2bf(b.z); r[7] = (short)f2bf(b.w);
  return r;
}

// ---------------------------------------------------------------------------
// KA: fused support+aggregate. 256 blocks x 512 threads, 1 block/CU.
// Block -> (batch b, quarter qt): 4 blocks per batch, all on XCD (b&7) so
// input[b]/adj[b] HBM fetches are shared through that XCD's L2.
// Per block: W^T -> LDS; full S[b] -> LDS stl[f][m] (4x redundant per batch,
// ~1.6 GFLOP total extra = negligible); then barrier-free aggregation of 64
// n-rows: 8 waves = 4 row-groups x 2 f-halves, A-frags streamed from global
// adj (cvt in reg), B-frags ds_read_b128 from stl. Plus beta-fill of
// non-crop out rows (hidden in latency slack).
// LDS 119.8KB. No St global round-trip.
// ---------------------------------------------------------------------------
__global__ __launch_bounds__(512, 1) void gcn_ka(
    const float* __restrict__ input, const float* __restrict__ adj,
    const float* __restrict__ W, const float* __restrict__ beta,
    float* __restrict__ out, float* __restrict__ Ocrop) {
  const int x = blockIdx.x & 7, y = blockIdx.x >> 3;
  const int b  = ((y >> 2) << 3) | x;  // batch
  const int qt = y & 3;                // quarter (64 n-rows)
  __shared__ ushort wt[128][136];   // W^T [f][i]         34816 B
  __shared__ ushort ain[64][136];   // input chunk [m][i] 17408 B
  __shared__ ushort stl[128][264];  // S^T full [f][m]    67584 B
  const int tid = threadIdx.x;
  const int l = tid & 63, w = tid >> 6;
  const int lr = l & 15, lg = l >> 4;

  // ---- beta-fill non-crop rows of out (independent; issue early) ----
  {
    const int gid = blockIdx.x * 512 + tid;
#pragma unroll
    for (int q = 0; q < 4; ++q) {
      const int g2 = gid + q * 131072;
      const int c4 = (g2 & 31) * 4;
      const int rr = (g2 >> 5) & 255;
      const int bb = g2 >> 13;
      const int n  = rr < 128 ? rr : rr + 256;
      const float4 bv =
          *reinterpret_cast<const float4*>(&beta[(size_t)n * F + c4]);
      *reinterpret_cast<float4*>(&out[((size_t)bb * NADJ + n) * F + c4]) = bv;
    }
  }

  // ---- stage W^T (once) ----
  {
    const int i0 = tid & 63;
    const int fq = (tid >> 6) * 16;
#pragma unroll
    for (int ih = 0; ih < 2; ++ih) {
      const int i = i0 + ih * 64;
      const float* wr = &W[(size_t)i * F + fq];
      float4 v[4];
#pragma unroll
      for (int q = 0; q < 4; ++q)
        v[q] = reinterpret_cast<const float4*>(wr)[q];
#pragma unroll
      for (int q = 0; q < 4; ++q) {
        wt[fq + q * 4 + 0][i] = f2bf(v[q].x);
        wt[fq + q * 4 + 1][i] = f2bf(v[q].y);
        wt[fq + q * 4 + 2][i] = f2bf(v[q].z);
        wt[fq + q * 4 + 3][i] = f2bf(v[q].w);
      }
    }
  }

  // ---- S[b] in 4 m-chunks of 64 -> stl ----
  const float* inb = input + ((size_t)b * NADJ + CROP0) * F;
  const int msub = (w & 3) * 16;   // wave m-subtile within chunk
  const int sf0  = (w >> 2) * 64;  // wave f-half
  for (int mc = 0; mc < CN; mc += 64) {
    if (mc > 0) __syncthreads();
    for (int idx = tid; idx < 64 * 32; idx += 512) {
      const int ml = idx >> 5, c4 = (idx & 31) * 4;
      const float4 v = *reinterpret_cast<const float4*>(
          &inb[(size_t)(mc + ml) * F + c4]);
      *reinterpret_cast<ushort4*>(&ain[ml][c4]) =
          make_ushort4(f2bf(v.x), f2bf(v.y), f2bf(v.z), f2bf(v.w));
    }
    __syncthreads();
    f32x4 sacc[4] = {};
#pragma unroll
    for (int ks = 0; ks < 4; ++ks) {
      const int k0 = ks * 32 + lg * 8;
      const short8 av = *reinterpret_cast<const short8*>(&ain[msub + lr][k0]);
#pragma unroll
      for (int fi = 0; fi < 4; ++fi) {
        const short8 bv =
            *reinterpret_cast<const short8*>(&wt[sf0 + fi * 16 + lr][k0]);
        sacc[fi] =
            __builtin_amdgcn_mfma_f32_16x16x32_bf16(av, bv, sacc[fi], 0, 0, 0);
      }
    }
#pragma unroll
    for (int fi = 0; fi < 4; ++fi)
      *reinterpret_cast<ushort4*>(
          &stl[sf0 + fi * 16 + lr][mc + msub + lg * 4]) =
          make_ushort4(f2bf(sacc[fi][0]), f2bf(sacc[fi][1]),
                       f2bf(sacc[fi][2]), f2bf(sacc[fi][3]));
  }
  __syncthreads();  // stl complete

  // ---- barrier-free aggregation: 64 rows, 4 row-groups x 2 f-halves ----
  const int n0  = qt * 64 + (w & 3) * 16;
  const int wf0 = (w >> 2) * 64;
  const float* a0 =
      adj + ((size_t)b * NADJ + CROP0 + n0 + lr) * NADJ + CROP0;
  f32x4 acc[4] = {};
#pragma unroll
  for (int ks = 0; ks < 8; ++ks) {
    const int k0 = ks * 32 + lg * 8;
    const float4 x0 = *reinterpret_cast<const float4*>(&a0[k0]);
    const float4 x1 = *reinterpret_cast<const float4*>(&a0[k0 + 4]);
    const short8 av = cvt8(x0, x1);
#pragma unroll
    for (int fi = 0; fi < 4; ++fi) {
      const short8 bv =
          *reinterpret_cast<const short8*>(&stl[wf0 + fi * 16 + lr][k0]);
      acc[fi] =
          __builtin_amdgcn_mfma_f32_16x16x32_bf16(av, bv, acc[fi], 0, 0, 0);
    }
  }
  // D: col(f)=lane&15, row(n)=4*(lane>>4)+reg
#pragma unroll
  for (int fi = 0; fi < 4; ++fi) {
    const int f = wf0 + fi * 16 + lr;
    const int n = n0 + lg * 4;
#pragma unroll
    for (int r = 0; r < 4; ++r)
      Ocrop[((size_t)b * CN + n + r) * F + f] = acc[fi][r];
  }
}

// ---------------------------------------------------------------------------
// KB: BN stats + normalize crop rows -> out.
// ---------------------------------------------------------------------------
__global__ __launch_bounds__(256) void gcn_kb(
    const float* __restrict__ Ocrop, float* __restrict__ out,
    const float* __restrict__ gamma, const float* __restrict__ beta) {
  __shared__ float s_l[256], s2_l[256], m_l[64], r_l[64];
  const int tid = threadIdx.x;
  const int jl = tid & 63, bg = tid >> 6;
  const int j  = blockIdx.x * 64 + jl;  // 0..32767 = nl*128+f
  const int nl = j >> 7, f = j & 127;
  const int nf = (CROP0 + nl) * F + f;
  const float* p = Ocrop + (size_t)j + (size_t)bg * 16 * CN * F;

  float x[16];
  float s = 0.f, s2 = 0.f;
#pragma unroll
  for (int bb = 0; bb < 16; ++bb) {
    x[bb] = p[(size_t)bb * CN * F];
    s += x[bb];
    s2 += x[bb] * x[bb];
  }
  s_l[tid]  = s;
  s2_l[tid] = s2;
  __syncthreads();
  if (tid < 64) {
    s  = s_l[jl] + s_l[64 + jl] + s_l[128 + jl] + s_l[192 + jl];
    s2 = s2_l[jl] + s2_l[64 + jl] + s2_l[128 + jl] + s2_l[192 + jl];
    const float mean = s * (1.f / BATCH);
    const float var  = s2 * (1.f / BATCH) - mean * mean;
    m_l[jl] = mean;
    r_l[jl] = rsqrtf(var + BN_EPS);
  }
  __syncthreads();
  const float mean = m_l[jl];
  const float a    = r_l[jl] * gamma[nf];
  const float c    = beta[nf] - mean * a;
#pragma unroll
  for (int bb = 0; bb < 16; ++bb)
    out[(size_t)nf + (size_t)(bg * 16 + bb) * NADJ * F] = x[bb] * a + c;
}

extern "C" void kernel_launch(void* const* d_in, const int* in_sizes, int n_in,
                              void* d_out, int out_size, void* d_ws,
                              size_t ws_size, hipStream_t stream) {
  const float* input = (const float*)d_in[0];
  const float* adj   = (const float*)d_in[1];
  const float* W     = (const float*)d_in[2];
  const float* gamma = (const float*)d_in[3];
  const float* beta  = (const float*)d_in[4];
  float* out = (float*)d_out;

  float* Ocrop = (float*)d_ws;  // 64*256*128 fp32 = 8.4 MB

  gcn_ka<<<256, 512, 0, stream>>>(input, adj, W, beta, out, Ocrop);
  gcn_kb<<<512, 256, 0, stream>>>(Ocrop, out, gamma, beta);
}

// Round 15
// 25.127 us; speedup vs baseline: 1.4505x; 1.0771x over previous
//
#include <hip/hip_runtime.h>
#include <hip/hip_bf16.h>

#define BATCH 64
#define NADJ  512
#define F     128
#define CROP0 128
#define CROP1 384
#define CN    256
#define BN_EPS 1e-5f

typedef __attribute__((ext_vector_type(8))) short short8;
typedef __attribute__((ext_vector_type(4))) float f32x4;

__device__ __forceinline__ ushort f2bf(float x) {
  __hip_bfloat16 h = __float2bfloat16(x);  // RNE
  return *reinterpret_cast<ushort*>(&h);
}

__device__ __forceinline__ short8 cvt8(const float4 a, const float4 b) {
  short8 r;
  r[0] = (short)f2bf(a.x); r[1] = (short)f2bf(a.y);
  r[2] = (short)f2bf(a.z); r[3] = (short)f2bf(a.w);
  r[4] = (short)f2bf(b.x); r[5] = (short)f2bf(b.y);
  r[6] = (short)f2bf(b.z); r[7] = (short)f2bf(b.w);
  return r;
}

// ---------------------------------------------------------------------------
// KA: fused support+aggregate. 256 blocks x 512 threads, 1 block/CU.
// Block -> (batch b, quarter qt), 4 blocks/batch on XCD (b&7).
// v15: (1) adj A-operand pre-issued at kernel entry (independent of S) so
// its HBM latency hides under the whole S-phase; agg loop is pure LDS+MFMA.
// (2) S-phase software-pipelined: prefetch chunk c+1 to regs during MFMA(c).
// (3) stl stride 268 (134 dw % 32 = 6): 16 row-lanes -> 16 distinct banks.
// LDS: wt 34816 + ain 17408 + stl 68608 = 120832 B.
// ---------------------------------------------------------------------------
__global__ __launch_bounds__(512, 1) void gcn_ka(
    const float* __restrict__ input, const float* __restrict__ adj,
    const float* __restrict__ W, const float* __restrict__ beta,
    float* __restrict__ out, float* __restrict__ Ocrop) {
  const int x = blockIdx.x & 7, y = blockIdx.x >> 3;
  const int b  = ((y >> 2) << 3) | x;  // batch
  const int qt = y & 3;                // quarter (64 n-rows)
  __shared__ ushort wt[128][136];   // W^T [f][i]
  __shared__ ushort ain[64][136];   // input chunk [m][i]
  __shared__ ushort stl[128][268];  // S^T full [f][m], 536B row stride
  const int tid = threadIdx.x;
  const int l = tid & 63, w = tid >> 6;
  const int lr = l & 15, lg = l >> 4;

  // ---- pre-issue agg A-operand: 16 x float4 of adj (used ~10us later) ----
  const int n0  = qt * 64 + (w & 3) * 16;
  const int wf0 = (w >> 2) * 64;
  const float* a0 =
      adj + ((size_t)b * NADJ + CROP0 + n0 + lr) * NADJ + CROP0;
  float4 xreg[16];
#pragma unroll
  for (int ks = 0; ks < 8; ++ks) {
    const int k0 = ks * 32 + lg * 8;
    xreg[2 * ks]     = *reinterpret_cast<const float4*>(&a0[k0]);
    xreg[2 * ks + 1] = *reinterpret_cast<const float4*>(&a0[k0 + 4]);
  }

  // ---- beta-fill non-crop rows of out (independent stores) ----
  {
    const int gid = blockIdx.x * 512 + tid;
#pragma unroll
    for (int q = 0; q < 4; ++q) {
      const int g2 = gid + q * 131072;
      const int c4 = (g2 & 31) * 4;
      const int rr = (g2 >> 5) & 255;
      const int bb = g2 >> 13;
      const int n  = rr < 128 ? rr : rr + 256;
      const float4 bv =
          *reinterpret_cast<const float4*>(&beta[(size_t)n * F + c4]);
      *reinterpret_cast<float4*>(&out[((size_t)bb * NADJ + n) * F + c4]) = bv;
    }
  }

  // ---- stage W^T (once) ----
  {
    const int i0 = tid & 63;
    const int fq = (tid >> 6) * 16;
#pragma unroll
    for (int ih = 0; ih < 2; ++ih) {
      const int i = i0 + ih * 64;
      const float* wr = &W[(size_t)i * F + fq];
      float4 v[4];
#pragma unroll
      for (int q = 0; q < 4; ++q)
        v[q] = reinterpret_cast<const float4*>(wr)[q];
#pragma unroll
      for (int q = 0; q < 4; ++q) {
        wt[fq + q * 4 + 0][i] = f2bf(v[q].x);
        wt[fq + q * 4 + 1][i] = f2bf(v[q].y);
        wt[fq + q * 4 + 2][i] = f2bf(v[q].z);
        wt[fq + q * 4 + 3][i] = f2bf(v[q].w);
      }
    }
  }

  // ---- S[b] in 4 m-chunks of 64, pipelined staging ----
  const float* inb = input + ((size_t)b * NADJ + CROP0) * F;
  const int msub = (w & 3) * 16;   // wave m-subtile within chunk
  const int sf0  = (w >> 2) * 64;  // wave f-half
  const int ml0  = tid >> 5;       // staging row 0..15 (+q*16)
  const int ic4  = (tid & 31) * 4; // staging col
  float4 pv[4];
#pragma unroll
  for (int q = 0; q < 4; ++q)
    pv[q] = *reinterpret_cast<const float4*>(
        &inb[(size_t)(ml0 + q * 16) * F + ic4]);

  for (int mc = 0; mc < CN; mc += 64) {
    // write prefetched chunk to ain
#pragma unroll
    for (int q = 0; q < 4; ++q)
      *reinterpret_cast<ushort4*>(&ain[ml0 + q * 16][ic4]) =
          make_ushort4(f2bf(pv[q].x), f2bf(pv[q].y), f2bf(pv[q].z),
                       f2bf(pv[q].w));
    __syncthreads();  // ain (and wt, first iter) visible
    // prefetch next chunk (overlaps MFMA below)
    if (mc + 64 < CN) {
#pragma unroll
      for (int q = 0; q < 4; ++q)
        pv[q] = *reinterpret_cast<const float4*>(
            &inb[(size_t)(mc + 64 + ml0 + q * 16) * F + ic4]);
    }
    f32x4 sacc[4] = {};
#pragma unroll
    for (int ks = 0; ks < 4; ++ks) {
      const int k0 = ks * 32 + lg * 8;
      const short8 av = *reinterpret_cast<const short8*>(&ain[msub + lr][k0]);
#pragma unroll
      for (int fi = 0; fi < 4; ++fi) {
        const short8 bv =
            *reinterpret_cast<const short8*>(&wt[sf0 + fi * 16 + lr][k0]);
        sacc[fi] =
            __builtin_amdgcn_mfma_f32_16x16x32_bf16(av, bv, sacc[fi], 0, 0, 0);
      }
    }
#pragma unroll
    for (int fi = 0; fi < 4; ++fi)
      *reinterpret_cast<ushort4*>(
          &stl[sf0 + fi * 16 + lr][mc + msub + lg * 4]) =
          make_ushort4(f2bf(sacc[fi][0]), f2bf(sacc[fi][1]),
                       f2bf(sacc[fi][2]), f2bf(sacc[fi][3]));
    __syncthreads();  // ain reads done; stl chunk visible
  }

  // ---- aggregation: pure LDS + MFMA (adj already in regs) ----
  f32x4 acc[4] = {};
#pragma unroll
  for (int ks = 0; ks < 8; ++ks) {
    const int k0 = ks * 32 + lg * 8;
    const short8 av = cvt8(xreg[2 * ks], xreg[2 * ks + 1]);
#pragma unroll
    for (int fi = 0; fi < 4; ++fi) {
      const short8 bv =
          *reinterpret_cast<const short8*>(&stl[wf0 + fi * 16 + lr][k0]);
      acc[fi] =
          __builtin_amdgcn_mfma_f32_16x16x32_bf16(av, bv, acc[fi], 0, 0, 0);
    }
  }
  // D: col(f)=lane&15, row(n)=4*(lane>>4)+reg
#pragma unroll
  for (int fi = 0; fi < 4; ++fi) {
    const int f = wf0 + fi * 16 + lr;
    const int n = n0 + lg * 4;
#pragma unroll
    for (int r = 0; r < 4; ++r)
      Ocrop[((size_t)b * CN + n + r) * F + f] = acc[fi][r];
  }
}

// ---------------------------------------------------------------------------
// KB: BN stats + normalize crop rows -> out.
// ---------------------------------------------------------------------------
__global__ __launch_bounds__(256) void gcn_kb(
    const float* __restrict__ Ocrop, float* __restrict__ out,
    const float* __restrict__ gamma, const float* __restrict__ beta) {
  __shared__ float s_l[256], s2_l[256], m_l[64], r_l[64];
  const int tid = threadIdx.x;
  const int jl = tid & 63, bg = tid >> 6;
  const int j  = blockIdx.x * 64 + jl;  // 0..32767 = nl*128+f
  const int nl = j >> 7, f = j & 127;
  const int nf = (CROP0 + nl) * F + f;
  const float* p = Ocrop + (size_t)j + (size_t)bg * 16 * CN * F;

  float x[16];
  float s = 0.f, s2 = 0.f;
#pragma unroll
  for (int bb = 0; bb < 16; ++bb) {
    x[bb] = p[(size_t)bb * CN * F];
    s += x[bb];
    s2 += x[bb] * x[bb];
  }
  s_l[tid]  = s;
  s2_l[tid] = s2;
  __syncthreads();
  if (tid < 64) {
    s  = s_l[jl] + s_l[64 + jl] + s_l[128 + jl] + s_l[192 + jl];
    s2 = s2_l[jl] + s2_l[64 + jl] + s2_l[128 + jl] + s2_l[192 + jl];
    const float mean = s * (1.f / BATCH);
    const float var  = s2 * (1.f / BATCH) - mean * mean;
    m_l[jl] = mean;
    r_l[jl] = rsqrtf(var + BN_EPS);
  }
  __syncthreads();
  const float mean = m_l[jl];
  const float a    = r_l[jl] * gamma[nf];
  const float c    = beta[nf] - mean * a;
#pragma unroll
  for (int bb = 0; bb < 16; ++bb)
    out[(size_t)nf + (size_t)(bg * 16 + bb) * NADJ * F] = x[bb] * a + c;
}

extern "C" void kernel_launch(void* const* d_in, const int* in_sizes, int n_in,
                              void* d_out, int out_size, void* d_ws,
                              size_t ws_size, hipStream_t stream) {
  const float* input = (const float*)d_in[0];
  const float* adj   = (const float*)d_in[1];
  const float* W     = (const float*)d_in[2];
  const float* gamma = (const float*)d_in[3];
  const float* beta  = (const float*)d_in[4];
  float* out = (float*)d_out;

  float* Ocrop = (float*)d_ws;  // 64*256*128 fp32 = 8.4 MB

  gcn_ka<<<256, 512, 0, stream>>>(input, adj, W, beta, out, Ocrop);
  gcn_kb<<<512, 256, 0, stream>>>(Ocrop, out, gamma, beta);
}